// Round 9
// baseline (7327.876 us; speedup 1.0000x reference)
//
#include <hip/hip_runtime.h>
#include <cmath>

#define BATCHN 256
#define SEQT   1024
#define EMBED  1024
#define HID    1024
#define VOCABN 32000

typedef __attribute__((ext_vector_type(8))) _Float16 half8;
typedef __attribute__((ext_vector_type(4))) _Float16 half4;
typedef __attribute__((ext_vector_type(4))) float    float4v;
typedef __attribute__((ext_vector_type(4))) unsigned int uint4v;

#define LOSCALE 4096.0f
#define LOINV   (1.0f/4096.0f)

union FU16 { _Float16 f; unsigned short u; };
__device__ inline unsigned short f16bits(_Float16 f){ FU16 t; t.f=f; return t.u; }
__device__ inline _Float16 bits16(unsigned short u){ FU16 t; t.u=u; return t.f; }

__device__ inline void async16(const void* g, void* l) {
  __builtin_amdgcn_global_load_lds(
      (const __attribute__((address_space(1))) void*)g,
      (__attribute__((address_space(3))) void*)l, 16, 0, 0);
}

// ---------------- f32 -> f16 convert ----------------
__global__ void convert_f32_f16(const float* __restrict__ in,
                                _Float16* __restrict__ out, int n) {
  int i = (blockIdx.x * blockDim.x + threadIdx.x) * 4;
  if (i + 3 < n) {
    float4v v = *reinterpret_cast<const float4v*>(in + i);
    half4 o;
#pragma unroll
    for (int j = 0; j < 4; ++j) o[j] = (_Float16)v[j];
    *reinterpret_cast<half4*>(out + i) = o;
  }
}

// ---------------- f32 -> f16 hi/lo split (lo pre-scaled by 2^12) ----------------
__global__ void split_f32_f16(const float* __restrict__ in,
                              _Float16* __restrict__ hi,
                              _Float16* __restrict__ lo, int n) {
  int i = (blockIdx.x * blockDim.x + threadIdx.x) * 4;
  if (i + 3 < n) {
    float4v v = *reinterpret_cast<const float4v*>(in + i);
    half4 h, l;
#pragma unroll
    for (int j = 0; j < 4; ++j) {
      h[j] = (_Float16)v[j];
      l[j] = (_Float16)((v[j] - (float)h[j]) * LOSCALE);
    }
    *reinterpret_cast<half4*>(hi + i) = h;
    *reinterpret_cast<half4*>(lo + i) = l;
  }
}

// ---------------- Phase 1: xi = emb[x] @ Wi^T + bi  (f16 MFMA, 128x128 tile) ----------------
// xi OUTPUT LAYOUT (scan-order blocks): block (tt, gb, gc) of 2KB:
//   xi[ (tt*256 + gb*16 + gc)*1024 + brow*64 + ncol ]  (halfs)
// so each scan WG consumes exactly one contiguous 2KB block per step.
__global__ __launch_bounds__(256, 2) void gemm_xi(
    const _Float16* __restrict__ embh,  // [VOCAB][1024] f16
    const _Float16* __restrict__ Wih,   // [1024][1024] f16 (n-major, k inner)
    const int* __restrict__ x,          // [256][1024]
    const float* __restrict__ bi,       // [1024]
    _Float16* __restrict__ xi,          // [Tc*256*1024] f16, block layout above
    int t0, int Tc)
{
  __shared__ __align__(16) _Float16 As[128 * 64];
  __shared__ __align__(16) _Float16 Bs[128 * 64];
  __shared__ __align__(16) _Float16 stage[128 * 132];
  __shared__ int toks[128];

  const int tid  = threadIdx.x;
  const int wid  = tid >> 6, lane = tid & 63;
  const int nt   = blockIdx.x & 7, mt = blockIdx.x >> 3;
  const int m0   = mt * 128, n0 = nt * 128;

  if (tid < 128) {
    int m  = m0 + tid;
    int tl = m >> 8;           // local t within chunk
    int b  = m & 255;          // batch row
    toks[tid] = x[b * SEQT + t0 + tl];
  }
  __syncthreads();

  const _Float16* aptr[4];
  const _Float16* bptr[4];
  int ldsoff[4];
#pragma unroll
  for (int i = 0; i < 4; ++i) {
    int idx = i * 256 + tid;
    int row = idx >> 3, kc = idx & 7;
    aptr[i]   = embh + (size_t)toks[row] * 1024 + kc * 8;
    bptr[i]   = Wih + ((size_t)(n0 + row) << 10) + kc * 8;
    ldsoff[i] = idx * 8;  // elements
  }

  float4v acc[4][4] = {};
  const int wm = wid & 1, wn = wid >> 1;
  const int cn = lane & 15, kg = lane >> 4;

  for (int k0 = 0; k0 < 1024; k0 += 64) {
#pragma unroll
    for (int i = 0; i < 4; ++i) {
      async16(aptr[i] + k0, &As[ldsoff[i]]);
      async16(bptr[i] + k0, &Bs[ldsoff[i]]);
    }
    __syncthreads();

    half8 a[4][2], b[4][2];
#pragma unroll
    for (int mf = 0; mf < 4; ++mf)
#pragma unroll
      for (int kf = 0; kf < 2; ++kf)
        a[mf][kf] = *reinterpret_cast<const half8*>(
            &As[(wm * 64 + mf * 16 + cn) * 64 + kf * 32 + kg * 8]);
#pragma unroll
    for (int nf = 0; nf < 4; ++nf)
#pragma unroll
      for (int kf = 0; kf < 2; ++kf)
        b[nf][kf] = *reinterpret_cast<const half8*>(
            &Bs[(wn * 64 + nf * 16 + cn) * 64 + kf * 32 + kg * 8]);

#pragma unroll
    for (int mf = 0; mf < 4; ++mf)
#pragma unroll
      for (int nf = 0; nf < 4; ++nf)
#pragma unroll
        for (int kf = 0; kf < 2; ++kf)
          acc[mf][nf] = __builtin_amdgcn_mfma_f32_16x16x32_f16(
              a[mf][kf], b[nf][kf], acc[mf][nf], 0, 0, 0);
    __syncthreads();
  }

  // epilogue: add bi, stage in LDS, 16B stores into scan-order blocks
#pragma unroll
  for (int nf = 0; nf < 4; ++nf) {
    int n = wn * 64 + nf * 16 + cn;
    float biv = bi[n0 + n];
#pragma unroll
    for (int mf = 0; mf < 4; ++mf) {
#pragma unroll
      for (int j = 0; j < 4; ++j) {
        int m = wm * 64 + mf * 16 + kg * 4 + j;
        stage[m * 132 + n] = (_Float16)(acc[mf][nf][j] + biv);
      }
    }
  }
  __syncthreads();
#pragma unroll
  for (int p = 0; p < 8; ++p) {
    int chunk = p * 256 + tid;
    int r = chunk >> 4, cc = chunk & 15;
    half4 v0 = *reinterpret_cast<const half4*>(stage + r * 132 + cc * 8);
    half4 v1 = *reinterpret_cast<const half4*>(stage + r * 132 + cc * 8 + 4);
    half8 o;
#pragma unroll
    for (int e = 0; e < 4; ++e) { o[e] = v0[e]; o[4 + e] = v1[e]; }
    int m  = m0 + r;                 // tt*256 + b
    int tt = m >> 8, b = m & 255;
    int n  = n0 + cc * 8;
    size_t addr = ((size_t)(tt * 256 + (b >> 4) * 16 + (n >> 6)) << 10)
                + (size_t)((b & 15) * 64 + (n & 63));
    *reinterpret_cast<half8*>(xi + addr) = o;
  }
}

// ---------------- Phase 2: persistent scan, 256 WGs = 16 batch-groups x 16 col-groups ----
// Fence-free device-coherent protocol (round-8, proven): sc0 sc1 stores/loads,
// explicit vmcnt drains, monotone per-WG flag lines. xi now read from per-step
// 2KB blocks (no strided HBM amplification).
__global__ __launch_bounds__(256, 1) void rnn_scan(
    const _Float16* __restrict__ Whig,  // [1024][1024] f16 (n-major)
    const _Float16* __restrict__ Wlog,  // [1024][1024] f16 residual * 2^12
    const float* __restrict__ bh,       // [1024]
    const _Float16* __restrict__ xi,    // block layout (see gemm_xi)
    float* __restrict__ hstate,         // [256][1024] f32
    float* __restrict__ out,            // [256][1024] f32
    unsigned int* __restrict__ hexA,    // [256][1024] u32 packed hi|lo<<16
    unsigned int* __restrict__ hexB,
    int* __restrict__ bar,              // [256 WGs][32 ints] flag lines (128B each)
    int t0, int Tc)
{
  __shared__ __align__(16) _Float16 Ahi[16 * 1024];
  __shared__ __align__(16) _Float16 Alo[16 * 1024];

  const int tid  = threadIdx.x;
  const int wv   = tid >> 6, lane = tid & 63;
  const int cn   = lane & 15, kg = lane >> 4;
  const int gb   = blockIdx.x >> 4;     // batch group (16 rows)
  const int gc   = blockIdx.x & 15;     // col group (64 cols)
  const int r0   = gb * 16;
  const int wcol = gc * 64 + wv * 16 + cn;  // this lane's output column

  // ---- Wh slice (streams from L2 each step; per-XCD footprint ~512KB) ----
  half8 whi[32], wlo[32];
  {
    const _Float16* wp = Whig + ((size_t)wcol << 10) + kg * 8;
    const _Float16* lp = Wlog + ((size_t)wcol << 10) + kg * 8;
#pragma unroll
    for (int kk = 0; kk < 32; ++kk) {
      whi[kk] = *reinterpret_cast<const half8*>(wp + kk * 32);
      wlo[kk] = *reinterpret_cast<const half8*>(lp + kk * 32);
    }
  }
  const float bhv = bh[wcol];

  // per-step xi block base offset for this thread (halfs)
  const size_t xibase = ((size_t)(gb * 16 + gc) << 10) + wv * 16 + cn;

  // ---- init LDS h-tile (swizzle: byte ^= (row&7)<<4) ----
  if (t0 == 0) {
#pragma unroll
    for (int p = 0; p < 8; ++p) {
      int idx = p * 256 + tid, row = idx >> 7, cc = idx & 127;
      int bo = (((row << 11) + cc * 16) ^ ((row & 7) << 4));
      half8 z = {0, 0, 0, 0, 0, 0, 0, 0};
      *reinterpret_cast<half8*>(reinterpret_cast<char*>(Ahi) + bo) = z;
      *reinterpret_cast<half8*>(reinterpret_cast<char*>(Alo) + bo) = z;
    }
  } else {
#pragma unroll
    for (int p = 0; p < 8; ++p) {
      int idx = p * 256 + tid, row = idx >> 7, cc = idx & 127;
      const float* hp = hstate + (((size_t)(r0 + row)) << 10) + cc * 8;
      half8 vh, vl;
#pragma unroll
      for (int e = 0; e < 8; ++e) {
        float f = hp[e];
        _Float16 hi = (_Float16)f;
        vh[e] = hi;
        vl[e] = (_Float16)((f - (float)hi) * LOSCALE);
      }
      int bo = (((row << 11) + cc * 16) ^ ((row & 7) << 4));
      *reinterpret_cast<half8*>(reinterpret_cast<char*>(Ahi) + bo) = vh;
      *reinterpret_cast<half8*>(reinterpret_cast<char*>(Alo) + bo) = vl;
    }
  }
  __syncthreads();

  // xi prefetch for step 0
  unsigned short xiu[4];
#pragma unroll
  for (int j = 0; j < 4; ++j)
    xiu[j] = *reinterpret_cast<const unsigned short*>(
        xi + xibase + (size_t)(kg * 4 + j) * 64);

  for (int tt = 0; tt < Tc; ++tt) {
    // ---- 3-pass compensated matvec, 6 interleaved accumulators ----
    float4v a1a = {}, a1b = {}, a2a = {}, a2b = {}, a3a = {}, a3b = {};
#pragma unroll
    for (int kk = 0; kk < 32; ++kk) {
      int ab = (((cn << 11) + kk * 64 + kg * 16) ^ ((cn & 7) << 4));
      half8 ah = *reinterpret_cast<const half8*>(reinterpret_cast<const char*>(Ahi) + ab);
      half8 al = *reinterpret_cast<const half8*>(reinterpret_cast<const char*>(Alo) + ab);
      if (kk & 1) {
        a1b = __builtin_amdgcn_mfma_f32_16x16x32_f16(ah, whi[kk], a1b, 0, 0, 0);
        a2b = __builtin_amdgcn_mfma_f32_16x16x32_f16(al, whi[kk], a2b, 0, 0, 0);
        a3b = __builtin_amdgcn_mfma_f32_16x16x32_f16(ah, wlo[kk], a3b, 0, 0, 0);
      } else {
        a1a = __builtin_amdgcn_mfma_f32_16x16x32_f16(ah, whi[kk], a1a, 0, 0, 0);
        a2a = __builtin_amdgcn_mfma_f32_16x16x32_f16(al, whi[kk], a2a, 0, 0, 0);
        a3a = __builtin_amdgcn_mfma_f32_16x16x32_f16(ah, wlo[kk], a3a, 0, 0, 0);
      }
    }

    // ---- epilogue ----
    const int tglob = t0 + tt;
    unsigned int* hexW = ((tt + 1) & 1) ? hexA : hexB;
#pragma unroll
    for (int j = 0; j < 4; ++j) {
      int row = r0 + kg * 4 + j;
      float v = (a1a[j] + a1b[j]) +
                (a2a[j] + a2b[j] + a3a[j] + a3b[j]) * LOINV +
                bhv + (float)bits16(xiu[j]);
      float h = tanhf(v);
      if (tt < Tc - 1) {
        _Float16 hi = (_Float16)h;
        _Float16 lo = (_Float16)((h - (float)hi) * LOSCALE);
        unsigned int u = (unsigned int)f16bits(hi) | ((unsigned int)f16bits(lo) << 16);
        // device-coherent store, no cache maintenance
        asm volatile("global_store_dword %0, %1, off sc0 sc1"
                     :: "v"((unsigned long long)(hexW + (((size_t)row) << 10) + wcol)),
                        "v"(u) : "memory");
      }
      if (tglob == SEQT - 1) out[(((size_t)row) << 10) + wcol] = h;
      else if (tt == Tc - 1) hstate[(((size_t)row) << 10) + wcol] = h;
    }
    if (tt == Tc - 1) break;  // no barrier/exchange after final step of chunk

    // xi prefetch for step tt+1 (issued before the barrier; hides latency)
#pragma unroll
    for (int j = 0; j < 4; ++j)
      xiu[j] = *reinterpret_cast<const unsigned short*>(
          xi + xibase + (((size_t)(tt + 1)) << 18) + (size_t)(kg * 4 + j) * 64);

    // ---- fence-free flag barrier ----
    asm volatile("s_waitcnt vmcnt(0)" ::: "memory");
    __syncthreads();
    const int target = tt + 1;
    if (tid == 0)
      asm volatile("global_store_dword %0, %1, off sc0 sc1"
                   :: "v"((unsigned long long)(bar + (gb * 16 + gc) * 32)),
                      "v"(target) : "memory");
    if (tid < 16) {
      const int* fp = bar + (gb * 16 + tid) * 32;
      for (;;) {
        int v;
        asm volatile("global_load_dword %0, %1, off sc0 sc1\n\t"
                     "s_waitcnt vmcnt(0)"
                     : "=v"(v) : "v"((unsigned long long)fp) : "memory");
        if (v >= target) break;
        __builtin_amdgcn_s_sleep(1);
      }
    }
    __syncthreads();

    // ---- exchange: device-coherent load of full 16x1024 h, unpack to LDS ----
    const unsigned int* src = ((tt + 1) & 1) ? hexA : hexB;
    uint4v ta[8], tb[8];
#pragma unroll
    for (int p = 0; p < 8; ++p) {
      int idx = p * 256 + tid, row = idx >> 7, cc = idx & 127;
      unsigned long long ap =
          (unsigned long long)(src + (((size_t)(r0 + row)) << 10) + cc * 8);
      asm volatile("global_load_dwordx4 %0, %1, off sc0 sc1"
                   : "=v"(ta[p]) : "v"(ap) : "memory");
      asm volatile("global_load_dwordx4 %0, %1, off sc0 sc1"
                   : "=v"(tb[p]) : "v"(ap + 16) : "memory");
    }
    asm volatile("s_waitcnt vmcnt(0)" ::: "memory");
    __builtin_amdgcn_sched_barrier(0);
#pragma unroll
    for (int p = 0; p < 8; ++p) {
      int idx = p * 256 + tid, row = idx >> 7, cc = idx & 127;
      half8 vh, vl;
#pragma unroll
      for (int e = 0; e < 8; ++e) {
        unsigned int u = (e < 4) ? ta[p][e] : tb[p][e - 4];
        vh[e] = bits16((unsigned short)(u & 0xffffu));
        vl[e] = bits16((unsigned short)(u >> 16));
      }
      int bo = (((row << 11) + cc * 16) ^ ((row & 7) << 4));
      *reinterpret_cast<half8*>(reinterpret_cast<char*>(Ahi) + bo) = vh;
      *reinterpret_cast<half8*>(reinterpret_cast<char*>(Alo) + bo) = vl;
    }
    __syncthreads();
  }
}

extern "C" void kernel_launch(void* const* d_in, const int* in_sizes, int n_in,
                              void* d_out, int out_size, void* d_ws, size_t ws_size,
                              hipStream_t stream) {
  const int*   x   = (const int*)  d_in[0];
  const float* emb = (const float*)d_in[1];
  const float* Wi  = (const float*)d_in[2];
  const float* bi  = (const float*)d_in[3];
  const float* Wh  = (const float*)d_in[4];
  const float* bh  = (const float*)d_in[5];
  float* out = (float*)d_out;

  char* ws = (char*)d_ws;
  size_t off = 0;
  auto alloc = [&](size_t bytes) -> void* {
    void* p = ws + off;
    off = (off + bytes + 255) & ~(size_t)255;
    return p;
  };

  _Float16* embh   = (_Float16*)alloc((size_t)VOCABN * EMBED * 2);
  _Float16* Wih    = (_Float16*)alloc((size_t)HID * EMBED * 2);
  _Float16* Whih   = (_Float16*)alloc((size_t)HID * HID * 2);
  _Float16* Wloh   = (_Float16*)alloc((size_t)HID * HID * 2);
  float*    hstate = (float*)   alloc((size_t)BATCHN * HID * 4);
  unsigned int* hexA = (unsigned int*)alloc((size_t)BATCHN * HID * 4);
  unsigned int* hexB = (unsigned int*)alloc((size_t)BATCHN * HID * 4);
  int* bar  = (int*)alloc(256 * 32 * 4);   // 128B flag line per WG
  size_t fixed = off;

  // largest power-of-two T-chunk whose xi buffer fits in remaining ws
  int Tc = 1024;
  while (Tc > 4 && fixed + (size_t)BATCHN * Tc * HID * 2 > ws_size) Tc >>= 1;
  _Float16* xih = (_Float16*)alloc((size_t)BATCHN * Tc * HID * 2);

  {
    int n = VOCABN * EMBED;
    convert_f32_f16<<<n / 1024, 256, 0, stream>>>(emb, embh, n);
    n = HID * EMBED;
    convert_f32_f16<<<n / 1024, 256, 0, stream>>>(Wi, Wih, n);
    n = HID * HID;
    split_f32_f16<<<n / 1024, 256, 0, stream>>>(Wh, Whih, Wloh, n);
  }

  for (int t0 = 0; t0 < SEQT; t0 += Tc) {
    int grid = (BATCHN * Tc / 128) * 8;  // 128x128 tiles over [256*Tc, 1024]
    gemm_xi<<<grid, 256, 0, stream>>>(embh, Wih, x, bi, xih, t0, Tc);
    hipMemsetAsync(bar, 0, 256 * 32 * 4, stream);
    rnn_scan<<<256, 256, 0, stream>>>(Whih, Wloh, bh, xih, hstate, out,
                                      hexA, hexB, bar, t0, Tc);
  }
}

// Round 10
// 6138.918 us; speedup vs baseline: 1.1937x; 1.1937x over previous
//
#include <hip/hip_runtime.h>
#include <cmath>

#define BATCHN 256
#define SEQT   1024
#define EMBED  1024
#define HID    1024
#define VOCABN 32000

typedef __attribute__((ext_vector_type(8))) _Float16 half8;
typedef __attribute__((ext_vector_type(4))) _Float16 half4;
typedef __attribute__((ext_vector_type(4))) float    float4v;
typedef __attribute__((ext_vector_type(4))) unsigned int uint4v;

#define LOSCALE 4096.0f
#define LOINV   (1.0f/4096.0f)

union FU16 { _Float16 f; unsigned short u; };
__device__ inline unsigned short f16bits(_Float16 f){ FU16 t; t.f=f; return t.u; }
__device__ inline _Float16 bits16(unsigned short u){ FU16 t; t.u=u; return t.f; }

__device__ inline void async16(const void* g, void* l) {
  __builtin_amdgcn_global_load_lds(
      (const __attribute__((address_space(1))) void*)g,
      (__attribute__((address_space(3))) void*)l, 16, 0, 0);
}

// ---------------- f32 -> f16 convert ----------------
__global__ void convert_f32_f16(const float* __restrict__ in,
                                _Float16* __restrict__ out, int n) {
  int i = (blockIdx.x * blockDim.x + threadIdx.x) * 4;
  if (i + 3 < n) {
    float4v v = *reinterpret_cast<const float4v*>(in + i);
    half4 o;
#pragma unroll
    for (int j = 0; j < 4; ++j) o[j] = (_Float16)v[j];
    *reinterpret_cast<half4*>(out + i) = o;
  }
}

// ---------------- f32 -> f16 hi/lo split (lo pre-scaled by 2^12) ----------------
__global__ void split_f32_f16(const float* __restrict__ in,
                              _Float16* __restrict__ hi,
                              _Float16* __restrict__ lo, int n) {
  int i = (blockIdx.x * blockDim.x + threadIdx.x) * 4;
  if (i + 3 < n) {
    float4v v = *reinterpret_cast<const float4v*>(in + i);
    half4 h, l;
#pragma unroll
    for (int j = 0; j < 4; ++j) {
      h[j] = (_Float16)v[j];
      l[j] = (_Float16)((v[j] - (float)h[j]) * LOSCALE);
    }
    *reinterpret_cast<half4*>(hi + i) = h;
    *reinterpret_cast<half4*>(lo + i) = l;
  }
}

// ---------------- Phase 1: xi = emb[x] @ Wi^T + bi  (f16 MFMA, 128x128 tile) ----------------
// xi OUTPUT LAYOUT (scan-order blocks): block (tt, gb, gc) of 2KB:
//   xi[ (tt*256 + gb*16 + gc)*1024 + brow*64 + ncol ]  (halfs)
__global__ __launch_bounds__(256, 2) void gemm_xi(
    const _Float16* __restrict__ embh,  // [VOCAB][1024] f16
    const _Float16* __restrict__ Wih,   // [1024][1024] f16 (n-major, k inner)
    const int* __restrict__ x,          // [256][1024]
    const float* __restrict__ bi,       // [1024]
    _Float16* __restrict__ xi,          // [Tc*256*1024] f16, block layout above
    int t0, int Tc)
{
  __shared__ __align__(16) _Float16 As[128 * 64];
  __shared__ __align__(16) _Float16 Bs[128 * 64];
  __shared__ __align__(16) _Float16 stage[128 * 132];
  __shared__ int toks[128];

  const int tid  = threadIdx.x;
  const int wid  = tid >> 6, lane = tid & 63;
  const int nt   = blockIdx.x & 7, mt = blockIdx.x >> 3;
  const int m0   = mt * 128, n0 = nt * 128;

  if (tid < 128) {
    int m  = m0 + tid;
    int tl = m >> 8;           // local t within chunk
    int b  = m & 255;          // batch row
    toks[tid] = x[b * SEQT + t0 + tl];
  }
  __syncthreads();

  const _Float16* aptr[4];
  const _Float16* bptr[4];
  int ldsoff[4];
#pragma unroll
  for (int i = 0; i < 4; ++i) {
    int idx = i * 256 + tid;
    int row = idx >> 3, kc = idx & 7;
    aptr[i]   = embh + (size_t)toks[row] * 1024 + kc * 8;
    bptr[i]   = Wih + ((size_t)(n0 + row) << 10) + kc * 8;
    ldsoff[i] = idx * 8;  // elements
  }

  float4v acc[4][4] = {};
  const int wm = wid & 1, wn = wid >> 1;
  const int cn = lane & 15, kg = lane >> 4;

  for (int k0 = 0; k0 < 1024; k0 += 64) {
#pragma unroll
    for (int i = 0; i < 4; ++i) {
      async16(aptr[i] + k0, &As[ldsoff[i]]);
      async16(bptr[i] + k0, &Bs[ldsoff[i]]);
    }
    __syncthreads();

    half8 a[4][2], b[4][2];
#pragma unroll
    for (int mf = 0; mf < 4; ++mf)
#pragma unroll
      for (int kf = 0; kf < 2; ++kf)
        a[mf][kf] = *reinterpret_cast<const half8*>(
            &As[(wm * 64 + mf * 16 + cn) * 64 + kf * 32 + kg * 8]);
#pragma unroll
    for (int nf = 0; nf < 4; ++nf)
#pragma unroll
      for (int kf = 0; kf < 2; ++kf)
        b[nf][kf] = *reinterpret_cast<const half8*>(
            &Bs[(wn * 64 + nf * 16 + cn) * 64 + kf * 32 + kg * 8]);

#pragma unroll
    for (int mf = 0; mf < 4; ++mf)
#pragma unroll
      for (int nf = 0; nf < 4; ++nf)
#pragma unroll
        for (int kf = 0; kf < 2; ++kf)
          acc[mf][nf] = __builtin_amdgcn_mfma_f32_16x16x32_f16(
              a[mf][kf], b[nf][kf], acc[mf][nf], 0, 0, 0);
    __syncthreads();
  }

  // epilogue: add bi, stage in LDS, 16B stores into scan-order blocks
#pragma unroll
  for (int nf = 0; nf < 4; ++nf) {
    int n = wn * 64 + nf * 16 + cn;
    float biv = bi[n0 + n];
#pragma unroll
    for (int mf = 0; mf < 4; ++mf) {
#pragma unroll
      for (int j = 0; j < 4; ++j) {
        int m = wm * 64 + mf * 16 + kg * 4 + j;
        stage[m * 132 + n] = (_Float16)(acc[mf][nf][j] + biv);
      }
    }
  }
  __syncthreads();
#pragma unroll
  for (int p = 0; p < 8; ++p) {
    int chunk = p * 256 + tid;
    int r = chunk >> 4, cc = chunk & 15;
    half4 v0 = *reinterpret_cast<const half4*>(stage + r * 132 + cc * 8);
    half4 v1 = *reinterpret_cast<const half4*>(stage + r * 132 + cc * 8 + 4);
    half8 o;
#pragma unroll
    for (int e = 0; e < 4; ++e) { o[e] = v0[e]; o[4 + e] = v1[e]; }
    int m  = m0 + r;                 // tt*256 + b
    int tt = m >> 8, b = m & 255;
    int n  = n0 + cc * 8;
    size_t addr = ((size_t)(tt * 256 + (b >> 4) * 16 + (n >> 6)) << 10)
                + (size_t)((b & 15) * 64 + (n & 63));
    *reinterpret_cast<half8*>(xi + addr) = o;
  }
}

// ---------------- Phase 2: persistent scan, 256 WGs = 16 batch-groups x 16 col-groups ----
// Fence-free device-coherent protocol (round-8, proven). NEW: Wh hi/lo held in
// 256 AGPRs, consumed directly as the MFMA B-operand via inline asm ("a"
// constraint) -- zero per-step Wh memory traffic, no copies (builtin forced
// VGPR operands; direct asm does not).
__global__ __launch_bounds__(256, 1) void rnn_scan(
    const _Float16* __restrict__ Whig,  // [1024][1024] f16 (n-major)
    const _Float16* __restrict__ Wlog,  // [1024][1024] f16 residual * 2^12
    const float* __restrict__ bh,       // [1024]
    const _Float16* __restrict__ xi,    // block layout (see gemm_xi)
    float* __restrict__ hstate,         // [256][1024] f32
    float* __restrict__ out,            // [256][1024] f32
    unsigned int* __restrict__ hexA,    // [256][1024] u32 packed hi|lo<<16
    unsigned int* __restrict__ hexB,
    int* __restrict__ bar,              // [256 WGs][32 ints] flag lines (128B each)
    int t0, int Tc)
{
  __shared__ __align__(16) _Float16 Ahi[16 * 1024];
  __shared__ __align__(16) _Float16 Alo[16 * 1024];

  const int tid  = threadIdx.x;
  const int wv   = tid >> 6, lane = tid & 63;
  const int cn   = lane & 15, kg = lane >> 4;
  const int gb   = blockIdx.x >> 4;     // batch group (16 rows)
  const int gc   = blockIdx.x & 15;     // col group (64 cols)
  const int r0   = gb * 16;
  const int wcol = gc * 64 + wv * 16 + cn;  // this lane's output column

  // ---- Wh slice -> AGPRs (one-time v_accvgpr_write; all uses are "a" operands) ----
  half8 whi[32], wlo[32];
  {
    const _Float16* wp = Whig + ((size_t)wcol << 10) + kg * 8;
    const _Float16* lp = Wlog + ((size_t)wcol << 10) + kg * 8;
#pragma unroll
    for (int kk = 0; kk < 32; ++kk) {
      whi[kk] = *reinterpret_cast<const half8*>(wp + kk * 32);
      wlo[kk] = *reinterpret_cast<const half8*>(lp + kk * 32);
    }
  }
  const float bhv = bh[wcol];

  // per-step xi block base offset for this thread (halfs)
  const size_t xibase = ((size_t)(gb * 16 + gc) << 10) + wv * 16 + cn;

  // ---- init LDS h-tile (swizzle: byte ^= (row&7)<<4) ----
  if (t0 == 0) {
#pragma unroll
    for (int p = 0; p < 8; ++p) {
      int idx = p * 256 + tid, row = idx >> 7, cc = idx & 127;
      int bo = (((row << 11) + cc * 16) ^ ((row & 7) << 4));
      half8 z = {0, 0, 0, 0, 0, 0, 0, 0};
      *reinterpret_cast<half8*>(reinterpret_cast<char*>(Ahi) + bo) = z;
      *reinterpret_cast<half8*>(reinterpret_cast<char*>(Alo) + bo) = z;
    }
  } else {
#pragma unroll
    for (int p = 0; p < 8; ++p) {
      int idx = p * 256 + tid, row = idx >> 7, cc = idx & 127;
      const float* hp = hstate + (((size_t)(r0 + row)) << 10) + cc * 8;
      half8 vh, vl;
#pragma unroll
      for (int e = 0; e < 8; ++e) {
        float f = hp[e];
        _Float16 hi = (_Float16)f;
        vh[e] = hi;
        vl[e] = (_Float16)((f - (float)hi) * LOSCALE);
      }
      int bo = (((row << 11) + cc * 16) ^ ((row & 7) << 4));
      *reinterpret_cast<half8*>(reinterpret_cast<char*>(Ahi) + bo) = vh;
      *reinterpret_cast<half8*>(reinterpret_cast<char*>(Alo) + bo) = vl;
    }
  }
  __syncthreads();

  // xi prefetch for step 0
  unsigned short xiu[4];
#pragma unroll
  for (int j = 0; j < 4; ++j)
    xiu[j] = *reinterpret_cast<const unsigned short*>(
        xi + xibase + (size_t)(kg * 4 + j) * 64);

  for (int tt = 0; tt < Tc; ++tt) {
    // ---- 3-pass compensated matvec; B operands straight from AGPRs ----
    float4v a1a = {}, a1b = {}, a2a = {}, a2b = {}, a3a = {}, a3b = {};
#pragma unroll
    for (int kk = 0; kk < 32; ++kk) {
      int ab = (((cn << 11) + kk * 64 + kg * 16) ^ ((cn & 7) << 4));
      half8 ah = *reinterpret_cast<const half8*>(reinterpret_cast<const char*>(Ahi) + ab);
      half8 al = *reinterpret_cast<const half8*>(reinterpret_cast<const char*>(Alo) + ab);
      if (kk & 1) {
        asm("v_mfma_f32_16x16x32_f16 %0, %1, %2, %0"
            : "+v"(a1b) : "v"(ah), "a"(whi[kk]));
        asm("v_mfma_f32_16x16x32_f16 %0, %1, %2, %0"
            : "+v"(a2b) : "v"(al), "a"(whi[kk]));
        asm("v_mfma_f32_16x16x32_f16 %0, %1, %2, %0"
            : "+v"(a3b) : "v"(ah), "a"(wlo[kk]));
      } else {
        asm("v_mfma_f32_16x16x32_f16 %0, %1, %2, %0"
            : "+v"(a1a) : "v"(ah), "a"(whi[kk]));
        asm("v_mfma_f32_16x16x32_f16 %0, %1, %2, %0"
            : "+v"(a2a) : "v"(al), "a"(whi[kk]));
        asm("v_mfma_f32_16x16x32_f16 %0, %1, %2, %0"
            : "+v"(a3a) : "v"(ah), "a"(wlo[kk]));
      }
    }
    // MFMA -> VALU read hazard cover (inline asm bypasses compiler hazard model)
    asm volatile("s_nop 7\n\ts_nop 7");

    // ---- epilogue ----
    const int tglob = t0 + tt;
    unsigned int* hexW = ((tt + 1) & 1) ? hexA : hexB;
#pragma unroll
    for (int j = 0; j < 4; ++j) {
      int row = r0 + kg * 4 + j;
      float v = (a1a[j] + a1b[j]) +
                (a2a[j] + a2b[j] + a3a[j] + a3b[j]) * LOINV +
                bhv + (float)bits16(xiu[j]);
      float h = tanhf(v);
      if (tt < Tc - 1) {
        _Float16 hi = (_Float16)h;
        _Float16 lo = (_Float16)((h - (float)hi) * LOSCALE);
        unsigned int u = (unsigned int)f16bits(hi) | ((unsigned int)f16bits(lo) << 16);
        asm volatile("global_store_dword %0, %1, off sc0 sc1"
                     :: "v"((unsigned long long)(hexW + (((size_t)row) << 10) + wcol)),
                        "v"(u) : "memory");
      }
      if (tglob == SEQT - 1) out[(((size_t)row) << 10) + wcol] = h;
      else if (tt == Tc - 1) hstate[(((size_t)row) << 10) + wcol] = h;
    }
    if (tt == Tc - 1) break;  // no barrier/exchange after final step of chunk

    // xi prefetch for step tt+1 (issued before the barrier; hides latency)
#pragma unroll
    for (int j = 0; j < 4; ++j)
      xiu[j] = *reinterpret_cast<const unsigned short*>(
          xi + xibase + (((size_t)(tt + 1)) << 18) + (size_t)(kg * 4 + j) * 64);

    // ---- fence-free flag barrier ----
    asm volatile("s_waitcnt vmcnt(0)" ::: "memory");
    __syncthreads();
    const int target = tt + 1;
    if (tid == 0)
      asm volatile("global_store_dword %0, %1, off sc0 sc1"
                   :: "v"((unsigned long long)(bar + (gb * 16 + gc) * 32)),
                      "v"(target) : "memory");
    if (tid < 16) {
      const int* fp = bar + (gb * 16 + tid) * 32;
      for (;;) {
        int v;
        asm volatile("global_load_dword %0, %1, off sc0 sc1\n\t"
                     "s_waitcnt vmcnt(0)"
                     : "=v"(v) : "v"((unsigned long long)fp) : "memory");
        if (v >= target) break;
        __builtin_amdgcn_s_sleep(1);
      }
    }
    __syncthreads();

    // ---- exchange: device-coherent load of full 16x1024 h, unpack to LDS ----
    const unsigned int* src = ((tt + 1) & 1) ? hexA : hexB;
    uint4v ta[8], tb[8];
#pragma unroll
    for (int p = 0; p < 8; ++p) {
      int idx = p * 256 + tid, row = idx >> 7, cc = idx & 127;
      unsigned long long ap =
          (unsigned long long)(src + (((size_t)(r0 + row)) << 10) + cc * 8);
      asm volatile("global_load_dwordx4 %0, %1, off sc0 sc1"
                   : "=v"(ta[p]) : "v"(ap) : "memory");
      asm volatile("global_load_dwordx4 %0, %1, off sc0 sc1"
                   : "=v"(tb[p]) : "v"(ap + 16) : "memory");
    }
    asm volatile("s_waitcnt vmcnt(0)" ::: "memory");
    __builtin_amdgcn_sched_barrier(0);
#pragma unroll
    for (int p = 0; p < 8; ++p) {
      int idx = p * 256 + tid, row = idx >> 7, cc = idx & 127;
      half8 vh, vl;
#pragma unroll
      for (int e = 0; e < 8; ++e) {
        unsigned int u = (e < 4) ? ta[p][e] : tb[p][e - 4];
        vh[e] = bits16((unsigned short)(u & 0xffffu));
        vl[e] = bits16((unsigned short)(u >> 16));
      }
      int bo = (((row << 11) + cc * 16) ^ ((row & 7) << 4));
      *reinterpret_cast<half8*>(reinterpret_cast<char*>(Ahi) + bo) = vh;
      *reinterpret_cast<half8*>(reinterpret_cast<char*>(Alo) + bo) = vl;
    }
    __syncthreads();
  }
}

extern "C" void kernel_launch(void* const* d_in, const int* in_sizes, int n_in,
                              void* d_out, int out_size, void* d_ws, size_t ws_size,
                              hipStream_t stream) {
  const int*   x   = (const int*)  d_in[0];
  const float* emb = (const float*)d_in[1];
  const float* Wi  = (const float*)d_in[2];
  const float* bi  = (const float*)d_in[3];
  const float* Wh  = (const float*)d_in[4];
  const float* bh  = (const float*)d_in[5];
  float* out = (float*)d_out;

  char* ws = (char*)d_ws;
  size_t off = 0;
  auto alloc = [&](size_t bytes) -> void* {
    void* p = ws + off;
    off = (off + bytes + 255) & ~(size_t)255;
    return p;
  };

  _Float16* embh   = (_Float16*)alloc((size_t)VOCABN * EMBED * 2);
  _Float16* Wih    = (_Float16*)alloc((size_t)HID * EMBED * 2);
  _Float16* Whih   = (_Float16*)alloc((size_t)HID * HID * 2);
  _Float16* Wloh   = (_Float16*)alloc((size_t)HID * HID * 2);
  float*    hstate = (float*)   alloc((size_t)BATCHN * HID * 4);
  unsigned int* hexA = (unsigned int*)alloc((size_t)BATCHN * HID * 4);
  unsigned int* hexB = (unsigned int*)alloc((size_t)BATCHN * HID * 4);
  int* bar  = (int*)alloc(256 * 32 * 4);   // 128B flag line per WG
  size_t fixed = off;

  // largest power-of-two T-chunk whose xi buffer fits in remaining ws
  int Tc = 1024;
  while (Tc > 4 && fixed + (size_t)BATCHN * Tc * HID * 2 > ws_size) Tc >>= 1;
  _Float16* xih = (_Float16*)alloc((size_t)BATCHN * Tc * HID * 2);

  {
    int n = VOCABN * EMBED;
    convert_f32_f16<<<n / 1024, 256, 0, stream>>>(emb, embh, n);
    n = HID * EMBED;
    convert_f32_f16<<<n / 1024, 256, 0, stream>>>(Wi, Wih, n);
    n = HID * HID;
    split_f32_f16<<<n / 1024, 256, 0, stream>>>(Wh, Whih, Wloh, n);
  }

  for (int t0 = 0; t0 < SEQT; t0 += Tc) {
    int grid = (BATCHN * Tc / 128) * 8;  // 128x128 tiles over [256*Tc, 1024]
    gemm_xi<<<grid, 256, 0, stream>>>(embh, Wih, x, bi, xih, t0, Tc);
    hipMemsetAsync(bar, 0, 256 * 32 * 4, stream);
    rnn_scan<<<256, 256, 0, stream>>>(Whih, Wloh, bh, xih, hstate, out,
                                      hexA, hexB, bar, t0, Tc);
  }
}

// Round 11
// 5166.751 us; speedup vs baseline: 1.4183x; 1.1882x over previous
//
#include <hip/hip_runtime.h>
#include <cmath>

#define BATCHN 256
#define SEQT   1024
#define EMBED  1024
#define HID    1024
#define VOCABN 32000

typedef __attribute__((ext_vector_type(8))) _Float16 half8;
typedef __attribute__((ext_vector_type(4))) _Float16 half4;
typedef __attribute__((ext_vector_type(4))) float    float4v;
typedef __attribute__((ext_vector_type(4))) unsigned int uint4v;

#define LOSCALE 4096.0f
#define LOINV   (1.0f/4096.0f)

union FU16 { _Float16 f; unsigned short u; };
__device__ inline unsigned short f16bits(_Float16 f){ FU16 t; t.f=f; return t.u; }
__device__ inline _Float16 bits16(unsigned short u){ FU16 t; t.u=u; return t.f; }

__device__ inline void async16(const void* g, void* l) {
  __builtin_amdgcn_global_load_lds(
      (const __attribute__((address_space(1))) void*)g,
      (__attribute__((address_space(3))) void*)l, 16, 0, 0);
}

// ---------------- f32 -> f16 convert ----------------
__global__ void convert_f32_f16(const float* __restrict__ in,
                                _Float16* __restrict__ out, int n) {
  int i = (blockIdx.x * blockDim.x + threadIdx.x) * 4;
  if (i + 3 < n) {
    float4v v = *reinterpret_cast<const float4v*>(in + i);
    half4 o;
#pragma unroll
    for (int j = 0; j < 4; ++j) o[j] = (_Float16)v[j];
    *reinterpret_cast<half4*>(out + i) = o;
  }
}

// ---------------- f32 -> f16 hi/lo split (lo pre-scaled by 2^12) ----------------
__global__ void split_f32_f16(const float* __restrict__ in,
                              _Float16* __restrict__ hi,
                              _Float16* __restrict__ lo, int n) {
  int i = (blockIdx.x * blockDim.x + threadIdx.x) * 4;
  if (i + 3 < n) {
    float4v v = *reinterpret_cast<const float4v*>(in + i);
    half4 h, l;
#pragma unroll
    for (int j = 0; j < 4; ++j) {
      h[j] = (_Float16)v[j];
      l[j] = (_Float16)((v[j] - (float)h[j]) * LOSCALE);
    }
    *reinterpret_cast<half4*>(hi + i) = h;
    *reinterpret_cast<half4*>(lo + i) = l;
  }
}

// ---------------- Phase 1: xi = emb[x] @ Wi^T + bi  (f16 MFMA, 128x128 tile) ----------------
// xi OUTPUT LAYOUT (scan-order blocks): block (tt, gb, gc) of 2KB:
//   xi[ (tt*256 + gb*16 + gc)*1024 + brow*64 + ncol ]  (halfs)
__global__ __launch_bounds__(256, 2) void gemm_xi(
    const _Float16* __restrict__ embh,  // [VOCAB][1024] f16
    const _Float16* __restrict__ Wih,   // [1024][1024] f16 (n-major, k inner)
    const int* __restrict__ x,          // [256][1024]
    const float* __restrict__ bi,       // [1024]
    _Float16* __restrict__ xi,          // [Tc*256*1024] f16, block layout above
    int t0, int Tc)
{
  __shared__ __align__(16) _Float16 As[128 * 64];
  __shared__ __align__(16) _Float16 Bs[128 * 64];
  __shared__ __align__(16) _Float16 stage[128 * 132];
  __shared__ int toks[128];

  const int tid  = threadIdx.x;
  const int wid  = tid >> 6, lane = tid & 63;
  const int nt   = blockIdx.x & 7, mt = blockIdx.x >> 3;
  const int m0   = mt * 128, n0 = nt * 128;

  if (tid < 128) {
    int m  = m0 + tid;
    int tl = m >> 8;           // local t within chunk
    int b  = m & 255;          // batch row
    toks[tid] = x[b * SEQT + t0 + tl];
  }
  __syncthreads();

  const _Float16* aptr[4];
  const _Float16* bptr[4];
  int ldsoff[4];
#pragma unroll
  for (int i = 0; i < 4; ++i) {
    int idx = i * 256 + tid;
    int row = idx >> 3, kc = idx & 7;
    aptr[i]   = embh + (size_t)toks[row] * 1024 + kc * 8;
    bptr[i]   = Wih + ((size_t)(n0 + row) << 10) + kc * 8;
    ldsoff[i] = idx * 8;  // elements
  }

  float4v acc[4][4] = {};
  const int wm = wid & 1, wn = wid >> 1;
  const int cn = lane & 15, kg = lane >> 4;

  for (int k0 = 0; k0 < 1024; k0 += 64) {
#pragma unroll
    for (int i = 0; i < 4; ++i) {
      async16(aptr[i] + k0, &As[ldsoff[i]]);
      async16(bptr[i] + k0, &Bs[ldsoff[i]]);
    }
    __syncthreads();

    half8 a[4][2], b[4][2];
#pragma unroll
    for (int mf = 0; mf < 4; ++mf)
#pragma unroll
      for (int kf = 0; kf < 2; ++kf)
        a[mf][kf] = *reinterpret_cast<const half8*>(
            &As[(wm * 64 + mf * 16 + cn) * 64 + kf * 32 + kg * 8]);
#pragma unroll
    for (int nf = 0; nf < 4; ++nf)
#pragma unroll
      for (int kf = 0; kf < 2; ++kf)
        b[nf][kf] = *reinterpret_cast<const half8*>(
            &Bs[(wn * 64 + nf * 16 + cn) * 64 + kf * 32 + kg * 8]);

#pragma unroll
    for (int mf = 0; mf < 4; ++mf)
#pragma unroll
      for (int nf = 0; nf < 4; ++nf)
#pragma unroll
        for (int kf = 0; kf < 2; ++kf)
          acc[mf][nf] = __builtin_amdgcn_mfma_f32_16x16x32_f16(
              a[mf][kf], b[nf][kf], acc[mf][nf], 0, 0, 0);
    __syncthreads();
  }

  // epilogue: add bi, stage in LDS, 16B stores into scan-order blocks
#pragma unroll
  for (int nf = 0; nf < 4; ++nf) {
    int n = wn * 64 + nf * 16 + cn;
    float biv = bi[n0 + n];
#pragma unroll
    for (int mf = 0; mf < 4; ++mf) {
#pragma unroll
      for (int j = 0; j < 4; ++j) {
        int m = wm * 64 + mf * 16 + kg * 4 + j;
        stage[m * 132 + n] = (_Float16)(acc[mf][nf][j] + biv);
      }
    }
  }
  __syncthreads();
#pragma unroll
  for (int p = 0; p < 8; ++p) {
    int chunk = p * 256 + tid;
    int r = chunk >> 4, cc = chunk & 15;
    half4 v0 = *reinterpret_cast<const half4*>(stage + r * 132 + cc * 8);
    half4 v1 = *reinterpret_cast<const half4*>(stage + r * 132 + cc * 8 + 4);
    half8 o;
#pragma unroll
    for (int e = 0; e < 4; ++e) { o[e] = v0[e]; o[4 + e] = v1[e]; }
    int m  = m0 + r;                 // tt*256 + b
    int tt = m >> 8, b = m & 255;
    int n  = n0 + cc * 8;
    size_t addr = ((size_t)(tt * 256 + (b >> 4) * 16 + (n >> 6)) << 10)
                + (size_t)((b & 15) * 64 + (n & 63));
    *reinterpret_cast<half8*>(xi + addr) = o;
  }
}

// ---------------- Phase 2: persistent scan, 256 WGs = 16 batch-groups x 16 col-groups ----
// Round-10 base (AGPR weights, fence-free sc0sc1 protocol) + split-half exchange
// pipelining: h stored as separate hi/lo f16 block buffers; consumer loads half0
// (cols 0..511, producers gc 0..7) and half1; half1 stays in registers across the
// next step's first MFMA half (counted vmcnt), landing in LDS just before kk16..31.
// Raw s_barrier (no compiler vmcnt drain) keeps half1 loads in flight.
__global__ __launch_bounds__(256, 1) void rnn_scan(
    const _Float16* __restrict__ Whig,   // [1024][1024] f16 (n-major)
    const _Float16* __restrict__ Wlog,   // [1024][1024] f16 residual * 2^12
    const float* __restrict__ bh,        // [1024]
    const _Float16* __restrict__ xi,     // block layout (see gemm_xi)
    float* __restrict__ hstate,          // [256][1024] f32
    float* __restrict__ out,             // [256][1024] f32
    _Float16* __restrict__ hexHiA,       // [256 blk][16 row][64 col] f16
    _Float16* __restrict__ hexLoA,
    _Float16* __restrict__ hexHiB,
    _Float16* __restrict__ hexLoB,
    int* __restrict__ bar,               // [256 WGs][32 ints] flag lines (128B each)
    int t0, int Tc)
{
  __shared__ __align__(16) _Float16 Ahi[16 * 1024];
  __shared__ __align__(16) _Float16 Alo[16 * 1024];

  const int tid  = threadIdx.x;
  const int wv   = tid >> 6, lane = tid & 63;
  const int cn   = lane & 15, kg = lane >> 4;
  const int gb   = blockIdx.x >> 4;     // batch group (16 rows)
  const int gc   = blockIdx.x & 15;     // col group (64 cols)
  const int r0   = gb * 16;
  const int wcol = gc * 64 + wv * 16 + cn;  // this lane's output column

  // ---- Wh slice -> AGPRs (all MFMA uses are "a" operands; zero per-step traffic) ----
  half8 whi[32], wlo[32];
  {
    const _Float16* wp = Whig + ((size_t)wcol << 10) + kg * 8;
    const _Float16* lp = Wlog + ((size_t)wcol << 10) + kg * 8;
#pragma unroll
    for (int kk = 0; kk < 32; ++kk) {
      whi[kk] = *reinterpret_cast<const half8*>(wp + kk * 32);
      wlo[kk] = *reinterpret_cast<const half8*>(lp + kk * 32);
    }
  }
  const float bhv = bh[wcol];

  // per-step xi block base offset for this thread (halfs)
  const size_t xibase = ((size_t)(gb * 16 + gc) << 10) + wv * 16 + cn;

  // ---- init LDS h-tile (swizzle: byte ^= (row&7)<<4) ----
  if (t0 == 0) {
#pragma unroll
    for (int p = 0; p < 8; ++p) {
      int idx = p * 256 + tid, row = idx >> 7, cc = idx & 127;
      int bo = (((row << 11) + cc * 16) ^ ((row & 7) << 4));
      half8 z = {0, 0, 0, 0, 0, 0, 0, 0};
      *reinterpret_cast<half8*>(reinterpret_cast<char*>(Ahi) + bo) = z;
      *reinterpret_cast<half8*>(reinterpret_cast<char*>(Alo) + bo) = z;
    }
  } else {
#pragma unroll
    for (int p = 0; p < 8; ++p) {
      int idx = p * 256 + tid, row = idx >> 7, cc = idx & 127;
      const float* hp = hstate + (((size_t)(r0 + row)) << 10) + cc * 8;
      half8 vh, vl;
#pragma unroll
      for (int e = 0; e < 8; ++e) {
        float f = hp[e];
        _Float16 hi = (_Float16)f;
        vh[e] = hi;
        vl[e] = (_Float16)((f - (float)hi) * LOSCALE);
      }
      int bo = (((row << 11) + cc * 16) ^ ((row & 7) << 4));
      *reinterpret_cast<half8*>(reinterpret_cast<char*>(Ahi) + bo) = vh;
      *reinterpret_cast<half8*>(reinterpret_cast<char*>(Alo) + bo) = vl;
    }
  }
  __syncthreads();

  // xi prefetch for step 0 (manual vmcnt bookkeeping -> asm loads)
  unsigned int xr[4];
#pragma unroll
  for (int j = 0; j < 4; ++j) {
    unsigned long long ap = (unsigned long long)(xi + xibase + (size_t)(kg * 4 + j) * 64);
    asm volatile("global_load_ushort %0, %1, off" : "=v"(xr[j]) : "v"(ap) : "memory");
  }

  uint4v uhi[4], ulo[4];   // half1 exchange data, pending in regs across loop top

  for (int tt = 0; tt < Tc; ++tt) {
    float4v a1a = {}, a1b = {}, a2a = {}, a2b = {}, a3a = {}, a3b = {};

    // ---- MFMA half0: kk 0..15 (h cols 0..511) ----
#pragma unroll
    for (int kk = 0; kk < 16; ++kk) {
      int ab = (((cn << 11) + kk * 64 + kg * 16) ^ ((cn & 7) << 4));
      half8 ah = *reinterpret_cast<const half8*>(reinterpret_cast<const char*>(Ahi) + ab);
      half8 al = *reinterpret_cast<const half8*>(reinterpret_cast<const char*>(Alo) + ab);
      if (kk & 1) {
        asm("v_mfma_f32_16x16x32_f16 %0, %1, %2, %0" : "+v"(a1b) : "v"(ah), "a"(whi[kk]));
        asm("v_mfma_f32_16x16x32_f16 %0, %1, %2, %0" : "+v"(a2b) : "v"(al), "a"(whi[kk]));
        asm("v_mfma_f32_16x16x32_f16 %0, %1, %2, %0" : "+v"(a3b) : "v"(ah), "a"(wlo[kk]));
      } else {
        asm("v_mfma_f32_16x16x32_f16 %0, %1, %2, %0" : "+v"(a1a) : "v"(ah), "a"(whi[kk]));
        asm("v_mfma_f32_16x16x32_f16 %0, %1, %2, %0" : "+v"(a2a) : "v"(al), "a"(whi[kk]));
        asm("v_mfma_f32_16x16x32_f16 %0, %1, %2, %0" : "+v"(a3a) : "v"(ah), "a"(wlo[kk]));
      }
    }

    // ---- half1 exchange data lands in LDS just-in-time (loads flew under kk0..15) ----
    if (tt != 0) {
      asm volatile("s_waitcnt vmcnt(0)" ::: "memory");
      __builtin_amdgcn_sched_barrier(0);
#pragma unroll
      for (int p = 0; p < 4; ++p) {
        int c = 1024 + p * 256 + tid;
        int gcb = c >> 7, rowl = (c >> 3) & 15, c8 = c & 7;
        int bo = (((rowl << 11) + gcb * 128 + c8 * 16) ^ ((rowl & 7) << 4));
        *reinterpret_cast<uint4v*>(reinterpret_cast<char*>(Ahi) + bo) = uhi[p];
        *reinterpret_cast<uint4v*>(reinterpret_cast<char*>(Alo) + bo) = ulo[p];
      }
      asm volatile("s_waitcnt lgkmcnt(0)" ::: "memory");
      __builtin_amdgcn_sched_barrier(0);
      __builtin_amdgcn_s_barrier();
    }

    // ---- MFMA half1: kk 16..31 (h cols 512..1023) ----
#pragma unroll
    for (int kk = 16; kk < 32; ++kk) {
      int ab = (((cn << 11) + kk * 64 + kg * 16) ^ ((cn & 7) << 4));
      half8 ah = *reinterpret_cast<const half8*>(reinterpret_cast<const char*>(Ahi) + ab);
      half8 al = *reinterpret_cast<const half8*>(reinterpret_cast<const char*>(Alo) + ab);
      if (kk & 1) {
        asm("v_mfma_f32_16x16x32_f16 %0, %1, %2, %0" : "+v"(a1b) : "v"(ah), "a"(whi[kk]));
        asm("v_mfma_f32_16x16x32_f16 %0, %1, %2, %0" : "+v"(a2b) : "v"(al), "a"(whi[kk]));
        asm("v_mfma_f32_16x16x32_f16 %0, %1, %2, %0" : "+v"(a3b) : "v"(ah), "a"(wlo[kk]));
      } else {
        asm("v_mfma_f32_16x16x32_f16 %0, %1, %2, %0" : "+v"(a1a) : "v"(ah), "a"(whi[kk]));
        asm("v_mfma_f32_16x16x32_f16 %0, %1, %2, %0" : "+v"(a2a) : "v"(al), "a"(whi[kk]));
        asm("v_mfma_f32_16x16x32_f16 %0, %1, %2, %0" : "+v"(a3a) : "v"(ah), "a"(wlo[kk]));
      }
    }
    // MFMA -> VALU acc-read hazard cover
    asm volatile("s_nop 7\n\ts_nop 7");
    // xi regs are long-arrived in steady state; free wait (covers tt==0 path)
    asm volatile("s_waitcnt vmcnt(0)" ::: "memory");

    // ---- epilogue ----
    const int tglob = t0 + tt;
    const int par = (tt + 1) & 1;
    _Float16* WHi = par ? hexHiA : hexHiB;
    _Float16* WLo = par ? hexLoA : hexLoB;
#pragma unroll
    for (int j = 0; j < 4; ++j) {
      int rowl = kg * 4 + j;
      int row  = r0 + rowl;
      float v = (a1a[j] + a1b[j]) +
                (a2a[j] + a2b[j] + a3a[j] + a3b[j]) * LOINV +
                bhv + (float)bits16((unsigned short)xr[j]);
      float ex = __expf(2.0f * v);
      float h  = 1.0f - 2.0f / (ex + 1.0f);
      if (tt < Tc - 1) {
        FU16 thi, tlo;
        thi.f = (_Float16)h;
        tlo.f = (_Float16)((h - (float)thi.f) * LOSCALE);
        size_t off = (((size_t)(gb * 16 + gc)) << 10) + rowl * 64 + wv * 16 + cn;
        asm volatile("global_store_short %0, %1, off sc0 sc1"
                     :: "v"((unsigned long long)(WHi + off)), "v"((unsigned int)thi.u) : "memory");
        asm volatile("global_store_short %0, %1, off sc0 sc1"
                     :: "v"((unsigned long long)(WLo + off)), "v"((unsigned int)tlo.u) : "memory");
      }
      if (tglob == SEQT - 1) out[(((size_t)row) << 10) + wcol] = h;
      else if (tt == Tc - 1) hstate[(((size_t)row) << 10) + wcol] = h;
    }
    if (tt == Tc - 1) break;  // no barrier/exchange after final step of chunk

    // ---- drain h stores, group-wide rendezvous, publish flag ----
    asm volatile("s_waitcnt vmcnt(0)" ::: "memory");
    __builtin_amdgcn_s_barrier();
    const int target = tt + 1;
    if (tid == 0)
      asm volatile("global_store_dword %0, %1, off sc0 sc1"
                   :: "v"((unsigned long long)(bar + (gb * 16 + gc) * 32)),
                      "v"(target) : "memory");

    // xi prefetch for step tt+1 (in flight through poll + exchange)
#pragma unroll
    for (int j = 0; j < 4; ++j) {
      unsigned long long ap = (unsigned long long)
          (xi + xibase + (((size_t)(tt + 1)) << 18) + (size_t)(kg * 4 + j) * 64);
      asm volatile("global_load_ushort %0, %1, off" : "=v"(xr[j]) : "v"(ap) : "memory");
    }

    // ---- poll all 16 producer flags (wave 0), then gate everyone ----
    if (tid < 16) {
      const int* fp = bar + (gb * 16 + tid) * 32;
      for (;;) {
        int v;
        asm volatile("global_load_dword %0, %1, off sc0 sc1\n\t"
                     "s_waitcnt vmcnt(0)"
                     : "=v"(v) : "v"((unsigned long long)fp) : "memory");
        if (v >= target) break;
        __builtin_amdgcn_s_sleep(1);
      }
    }
    __builtin_amdgcn_s_barrier();

    // ---- issue exchange loads: half0 (8) then half1 (8) ----
    const _Float16* SHi = par ? hexHiA : hexHiB;
    const _Float16* SLo = par ? hexLoA : hexLoB;
    uint4v thi0[4], tlo0[4];
#pragma unroll
    for (int p = 0; p < 4; ++p) {
      int c = p * 256 + tid;
      int gcb = c >> 7, rowl = (c >> 3) & 15, c8 = c & 7;
      size_t off = (((size_t)(gb * 16 + gcb)) << 10) + rowl * 64 + c8 * 8;
      asm volatile("global_load_dwordx4 %0, %1, off sc0 sc1"
                   : "=v"(thi0[p]) : "v"((unsigned long long)(SHi + off)) : "memory");
      asm volatile("global_load_dwordx4 %0, %1, off sc0 sc1"
                   : "=v"(tlo0[p]) : "v"((unsigned long long)(SLo + off)) : "memory");
    }
#pragma unroll
    for (int p = 0; p < 4; ++p) {
      int c = 1024 + p * 256 + tid;
      int gcb = c >> 7, rowl = (c >> 3) & 15, c8 = c & 7;
      size_t off = (((size_t)(gb * 16 + gcb)) << 10) + rowl * 64 + c8 * 8;
      asm volatile("global_load_dwordx4 %0, %1, off sc0 sc1"
                   : "=v"(uhi[p]) : "v"((unsigned long long)(SHi + off)) : "memory");
      asm volatile("global_load_dwordx4 %0, %1, off sc0 sc1"
                   : "=v"(ulo[p]) : "v"((unsigned long long)(SLo + off)) : "memory");
    }
    // counted wait: half0 arrived, 8 half1 loads stay in flight
    asm volatile("s_waitcnt vmcnt(8)" ::: "memory");
    __builtin_amdgcn_sched_barrier(0);
#pragma unroll
    for (int p = 0; p < 4; ++p) {
      int c = p * 256 + tid;
      int gcb = c >> 7, rowl = (c >> 3) & 15, c8 = c & 7;
      int bo = (((rowl << 11) + gcb * 128 + c8 * 16) ^ ((rowl & 7) << 4));
      *reinterpret_cast<uint4v*>(reinterpret_cast<char*>(Ahi) + bo) = thi0[p];
      *reinterpret_cast<uint4v*>(reinterpret_cast<char*>(Alo) + bo) = tlo0[p];
    }
    asm volatile("s_waitcnt lgkmcnt(0)" ::: "memory");
    __builtin_amdgcn_sched_barrier(0);
    __builtin_amdgcn_s_barrier();
    // loop: MFMA kk0..15 runs on half0 while half1 loads land
  }
}

extern "C" void kernel_launch(void* const* d_in, const int* in_sizes, int n_in,
                              void* d_out, int out_size, void* d_ws, size_t ws_size,
                              hipStream_t stream) {
  const int*   x   = (const int*)  d_in[0];
  const float* emb = (const float*)d_in[1];
  const float* Wi  = (const float*)d_in[2];
  const float* bi  = (const float*)d_in[3];
  const float* Wh  = (const float*)d_in[4];
  const float* bh  = (const float*)d_in[5];
  float* out = (float*)d_out;

  char* ws = (char*)d_ws;
  size_t off = 0;
  auto alloc = [&](size_t bytes) -> void* {
    void* p = ws + off;
    off = (off + bytes + 255) & ~(size_t)255;
    return p;
  };

  _Float16* embh   = (_Float16*)alloc((size_t)VOCABN * EMBED * 2);
  _Float16* Wih    = (_Float16*)alloc((size_t)HID * EMBED * 2);
  _Float16* Whih   = (_Float16*)alloc((size_t)HID * HID * 2);
  _Float16* Wloh   = (_Float16*)alloc((size_t)HID * HID * 2);
  float*    hstate = (float*)   alloc((size_t)BATCHN * HID * 4);
  _Float16* hexHiA = (_Float16*)alloc((size_t)BATCHN * HID * 2);
  _Float16* hexLoA = (_Float16*)alloc((size_t)BATCHN * HID * 2);
  _Float16* hexHiB = (_Float16*)alloc((size_t)BATCHN * HID * 2);
  _Float16* hexLoB = (_Float16*)alloc((size_t)BATCHN * HID * 2);
  int* bar  = (int*)alloc(256 * 32 * 4);   // 128B flag line per WG
  size_t fixed = off;

  // largest power-of-two T-chunk whose xi buffer fits in remaining ws
  int Tc = 1024;
  while (Tc > 4 && fixed + (size_t)BATCHN * Tc * HID * 2 > ws_size) Tc >>= 1;
  _Float16* xih = (_Float16*)alloc((size_t)BATCHN * Tc * HID * 2);

  {
    int n = VOCABN * EMBED;
    convert_f32_f16<<<n / 1024, 256, 0, stream>>>(emb, embh, n);
    n = HID * EMBED;
    convert_f32_f16<<<n / 1024, 256, 0, stream>>>(Wi, Wih, n);
    n = HID * HID;
    split_f32_f16<<<n / 1024, 256, 0, stream>>>(Wh, Whih, Wloh, n);
  }

  for (int t0 = 0; t0 < SEQT; t0 += Tc) {
    int grid = (BATCHN * Tc / 128) * 8;  // 128x128 tiles over [256*Tc, 1024]
    gemm_xi<<<grid, 256, 0, stream>>>(embh, Wih, x, bi, xih, t0, Tc);
    hipMemsetAsync(bar, 0, 256 * 32 * 4, stream);
    rnn_scan<<<256, 256, 0, stream>>>(Whih, Wloh, bh, xih, hstate, out,
                                      hexHiA, hexLoA, hexHiB, hexLoB, bar, t0, Tc);
  }
}

// Round 12
// 5014.230 us; speedup vs baseline: 1.4614x; 1.0304x over previous
//
#include <hip/hip_runtime.h>
#include <cmath>

#define BATCHN 256
#define SEQT   1024
#define EMBED  1024
#define HID    1024
#define VOCABN 32000

typedef __attribute__((ext_vector_type(8))) _Float16 half8;
typedef __attribute__((ext_vector_type(4))) _Float16 half4;
typedef __attribute__((ext_vector_type(4))) float    float4v;
typedef __attribute__((ext_vector_type(4))) unsigned int uint4v;

#define LOSCALE 4096.0f
#define LOINV   (1.0f/4096.0f)

union FU16 { _Float16 f; unsigned short u; };
__device__ inline unsigned short f16bits(_Float16 f){ FU16 t; t.f=f; return t.u; }
__device__ inline _Float16 bits16(unsigned short u){ FU16 t; t.u=u; return t.f; }

__device__ inline void async16(const void* g, void* l) {
  __builtin_amdgcn_global_load_lds(
      (const __attribute__((address_space(1))) void*)g,
      (__attribute__((address_space(3))) void*)l, 16, 0, 0);
}

// ---------------- f32 -> f16 convert ----------------
__global__ void convert_f32_f16(const float* __restrict__ in,
                                _Float16* __restrict__ out, int n) {
  int i = (blockIdx.x * blockDim.x + threadIdx.x) * 4;
  if (i + 3 < n) {
    float4v v = *reinterpret_cast<const float4v*>(in + i);
    half4 o;
#pragma unroll
    for (int j = 0; j < 4; ++j) o[j] = (_Float16)v[j];
    *reinterpret_cast<half4*>(out + i) = o;
  }
}

// ---------------- f32 -> f16 hi/lo split (lo pre-scaled by 2^12) ----------------
__global__ void split_f32_f16(const float* __restrict__ in,
                              _Float16* __restrict__ hi,
                              _Float16* __restrict__ lo, int n) {
  int i = (blockIdx.x * blockDim.x + threadIdx.x) * 4;
  if (i + 3 < n) {
    float4v v = *reinterpret_cast<const float4v*>(in + i);
    half4 h, l;
#pragma unroll
    for (int j = 0; j < 4; ++j) {
      h[j] = (_Float16)v[j];
      l[j] = (_Float16)((v[j] - (float)h[j]) * LOSCALE);
    }
    *reinterpret_cast<half4*>(hi + i) = h;
    *reinterpret_cast<half4*>(lo + i) = l;
  }
}

// ---------------- Phase 1: xi = emb[x] @ Wi^T + bi  (f16 MFMA, 128x128 tile) ----------------
// xi OUTPUT LAYOUT (scan-order blocks): block (tt, gb, gc) of 2KB:
//   xi[ (tt*256 + gb*16 + gc)*1024 + brow*64 + ncol ]  (halfs)
__global__ __launch_bounds__(256, 2) void gemm_xi(
    const _Float16* __restrict__ embh,  // [VOCAB][1024] f16
    const _Float16* __restrict__ Wih,   // [1024][1024] f16 (n-major, k inner)
    const int* __restrict__ x,          // [256][1024]
    const float* __restrict__ bi,       // [1024]
    _Float16* __restrict__ xi,          // [Tc*256*1024] f16, block layout above
    int t0, int Tc)
{
  __shared__ __align__(16) _Float16 As[128 * 64];
  __shared__ __align__(16) _Float16 Bs[128 * 64];
  __shared__ __align__(16) _Float16 stage[128 * 132];
  __shared__ int toks[128];

  const int tid  = threadIdx.x;
  const int wid  = tid >> 6, lane = tid & 63;
  const int nt   = blockIdx.x & 7, mt = blockIdx.x >> 3;
  const int m0   = mt * 128, n0 = nt * 128;

  if (tid < 128) {
    int m  = m0 + tid;
    int tl = m >> 8;           // local t within chunk
    int b  = m & 255;          // batch row
    toks[tid] = x[b * SEQT + t0 + tl];
  }
  __syncthreads();

  const _Float16* aptr[4];
  const _Float16* bptr[4];
  int ldsoff[4];
#pragma unroll
  for (int i = 0; i < 4; ++i) {
    int idx = i * 256 + tid;
    int row = idx >> 3, kc = idx & 7;
    aptr[i]   = embh + (size_t)toks[row] * 1024 + kc * 8;
    bptr[i]   = Wih + ((size_t)(n0 + row) << 10) + kc * 8;
    ldsoff[i] = idx * 8;  // elements
  }

  float4v acc[4][4] = {};
  const int wm = wid & 1, wn = wid >> 1;
  const int cn = lane & 15, kg = lane >> 4;

  for (int k0 = 0; k0 < 1024; k0 += 64) {
#pragma unroll
    for (int i = 0; i < 4; ++i) {
      async16(aptr[i] + k0, &As[ldsoff[i]]);
      async16(bptr[i] + k0, &Bs[ldsoff[i]]);
    }
    __syncthreads();

    half8 a[4][2], b[4][2];
#pragma unroll
    for (int mf = 0; mf < 4; ++mf)
#pragma unroll
      for (int kf = 0; kf < 2; ++kf)
        a[mf][kf] = *reinterpret_cast<const half8*>(
            &As[(wm * 64 + mf * 16 + cn) * 64 + kf * 32 + kg * 8]);
#pragma unroll
    for (int nf = 0; nf < 4; ++nf)
#pragma unroll
      for (int kf = 0; kf < 2; ++kf)
        b[nf][kf] = *reinterpret_cast<const half8*>(
            &Bs[(wn * 64 + nf * 16 + cn) * 64 + kf * 32 + kg * 8]);

#pragma unroll
    for (int mf = 0; mf < 4; ++mf)
#pragma unroll
      for (int nf = 0; nf < 4; ++nf)
#pragma unroll
        for (int kf = 0; kf < 2; ++kf)
          acc[mf][nf] = __builtin_amdgcn_mfma_f32_16x16x32_f16(
              a[mf][kf], b[nf][kf], acc[mf][nf], 0, 0, 0);
    __syncthreads();
  }

  // epilogue: add bi, stage in LDS, 16B stores into scan-order blocks
#pragma unroll
  for (int nf = 0; nf < 4; ++nf) {
    int n = wn * 64 + nf * 16 + cn;
    float biv = bi[n0 + n];
#pragma unroll
    for (int mf = 0; mf < 4; ++mf) {
#pragma unroll
      for (int j = 0; j < 4; ++j) {
        int m = wm * 64 + mf * 16 + kg * 4 + j;
        stage[m * 132 + n] = (_Float16)(acc[mf][nf][j] + biv);
      }
    }
  }
  __syncthreads();
#pragma unroll
  for (int p = 0; p < 8; ++p) {
    int chunk = p * 256 + tid;
    int r = chunk >> 4, cc = chunk & 15;
    half4 v0 = *reinterpret_cast<const half4*>(stage + r * 132 + cc * 8);
    half4 v1 = *reinterpret_cast<const half4*>(stage + r * 132 + cc * 8 + 4);
    half8 o;
#pragma unroll
    for (int e = 0; e < 4; ++e) { o[e] = v0[e]; o[4 + e] = v1[e]; }
    int m  = m0 + r;                 // tt*256 + b
    int tt = m >> 8, b = m & 255;
    int n  = n0 + cc * 8;
    size_t addr = ((size_t)(tt * 256 + (b >> 4) * 16 + (n >> 6)) << 10)
                + (size_t)((b & 15) * 64 + (n & 63));
    *reinterpret_cast<half8*>(xi + addr) = o;
  }
}

// ---------------- Phase 2: persistent scan, 256 WGs = 16 batch-groups x 16 col-groups ----
// K-SPLIT over waves: wave wv covers kk in [wv*8, wv*8+8) for ALL 64 output cols.
// Weights (hi/lo) for that slice live in 256 AGPRs (MFMA "a" operands, r10-proven).
// Each wave reads only its 256-col slice of h from LDS (4x less LDS BW) and the
// exchange is wave-private (no mid-exchange barriers). Partial sums reduced via
// padded LDS. Inter-WG protocol identical to round 11 (fence-free sc0sc1 flags).
__global__ __launch_bounds__(256, 1) void rnn_scan(
    const _Float16* __restrict__ Whig,   // [1024][1024] f16 (n-major)
    const _Float16* __restrict__ Wlog,   // [1024][1024] f16 residual * 2^12
    const float* __restrict__ bh,        // [1024]
    const _Float16* __restrict__ xi,     // block layout (see gemm_xi)
    float* __restrict__ hstate,          // [256][1024] f32
    float* __restrict__ out,             // [256][1024] f32
    _Float16* __restrict__ hexHiA,       // [256 blk][16 row][64 col] f16
    _Float16* __restrict__ hexLoA,
    _Float16* __restrict__ hexHiB,
    _Float16* __restrict__ hexLoB,
    int* __restrict__ bar,               // [256 WGs][32 ints] flag lines (128B each)
    int t0, int Tc)
{
  __shared__ __align__(16) _Float16 Ahi[16 * 1024];
  __shared__ __align__(16) _Float16 Alo[16 * 1024];
  __shared__ __align__(16) float    part[4 * 64 * 20];  // [wave][col64][16 +4 pad]

  const int tid  = threadIdx.x;
  const int wv   = tid >> 6, lane = tid & 63;
  const int cn   = lane & 15, kg = lane >> 4;
  const int gb   = blockIdx.x >> 4;     // batch group (16 rows)
  const int gc   = blockIdx.x & 15;     // col group (64 cols)
  const int r0   = gb * 16;
  const int wcol = gc * 64 + wv * 16 + cn;  // this lane's OUTPUT column (epilogue role)

  // ---- Wh K-slice -> AGPRs: fragment (coltile c, kkl): cols gc*64+c*16+cn,
  //      k = (wv*8+kkl)*32 + kg*8 .. +8. 32 half8 hi + 32 lo = 256 AGPRs.
  half8 whi[32], wlo[32];
#pragma unroll
  for (int c = 0; c < 4; ++c)
#pragma unroll
    for (int kkl = 0; kkl < 8; ++kkl) {
      int col = gc * 64 + c * 16 + cn;
      int k   = (wv * 8 + kkl) * 32 + kg * 8;
      whi[c * 8 + kkl] = *reinterpret_cast<const half8*>(Whig + ((size_t)col << 10) + k);
      wlo[c * 8 + kkl] = *reinterpret_cast<const half8*>(Wlog + ((size_t)col << 10) + k);
    }
  const float bhv = bh[wcol];

  // per-step xi block base offset for this thread (halfs)
  const size_t xibase = ((size_t)(gb * 16 + gc) << 10) + wv * 16 + cn;

  // ---- init LDS h-tile (swizzle: byte ^= (row&7)<<4) ----
  if (t0 == 0) {
#pragma unroll
    for (int p = 0; p < 8; ++p) {
      int idx = p * 256 + tid, row = idx >> 7, cc = idx & 127;
      int bo = (((row << 11) + cc * 16) ^ ((row & 7) << 4));
      half8 z = {0, 0, 0, 0, 0, 0, 0, 0};
      *reinterpret_cast<half8*>(reinterpret_cast<char*>(Ahi) + bo) = z;
      *reinterpret_cast<half8*>(reinterpret_cast<char*>(Alo) + bo) = z;
    }
  } else {
#pragma unroll
    for (int p = 0; p < 8; ++p) {
      int idx = p * 256 + tid, row = idx >> 7, cc = idx & 127;
      const float* hp = hstate + (((size_t)(r0 + row)) << 10) + cc * 8;
      half8 vh, vl;
#pragma unroll
      for (int e = 0; e < 8; ++e) {
        float f = hp[e];
        _Float16 hi = (_Float16)f;
        vh[e] = hi;
        vl[e] = (_Float16)((f - (float)hi) * LOSCALE);
      }
      int bo = (((row << 11) + cc * 16) ^ ((row & 7) << 4));
      *reinterpret_cast<half8*>(reinterpret_cast<char*>(Ahi) + bo) = vh;
      *reinterpret_cast<half8*>(reinterpret_cast<char*>(Alo) + bo) = vl;
    }
  }
  __syncthreads();

  // xi prefetch for step 0
  unsigned int xr[4];
#pragma unroll
  for (int j = 0; j < 4; ++j) {
    unsigned long long ap = (unsigned long long)(xi + xibase + (size_t)(kg * 4 + j) * 64);
    asm volatile("global_load_ushort %0, %1, off" : "=v"(xr[j]) : "v"(ap) : "memory");
  }

  uint4v u1h[4], u1l[4];   // second half of wave's exchange slice, pending in regs

#define MFMA_Q(K0, K1)                                                          \
  _Pragma("unroll")                                                             \
  for (int kkl = (K0); kkl < (K1); ++kkl) {                                     \
    int ab = (((cn << 11) + (wv * 8 + kkl) * 64 + kg * 16) ^ ((cn & 7) << 4));  \
    half8 ah = *reinterpret_cast<const half8*>(reinterpret_cast<const char*>(Ahi) + ab); \
    half8 al = *reinterpret_cast<const half8*>(reinterpret_cast<const char*>(Alo) + ab); \
    _Pragma("unroll")                                                           \
    for (int c = 0; c < 4; ++c) {                                               \
      asm("v_mfma_f32_16x16x32_f16 %0, %1, %2, %0" : "+v"(ac1[c]) : "v"(ah), "a"(whi[c * 8 + kkl])); \
      asm("v_mfma_f32_16x16x32_f16 %0, %1, %2, %0" : "+v"(ac2[c]) : "v"(al), "a"(whi[c * 8 + kkl])); \
      asm("v_mfma_f32_16x16x32_f16 %0, %1, %2, %0" : "+v"(ac3[c]) : "v"(ah), "a"(wlo[c * 8 + kkl])); \
    }                                                                           \
  }

  for (int tt = 0; tt < Tc; ++tt) {
    float4v ac1[4] = {}, ac2[4] = {}, ac3[4] = {};

    // ---- MFMA kkl 0..3 (cols wv*256 .. wv*256+127; LDS written pre-loop) ----
    MFMA_Q(0, 4)

    // ---- wave-private: land second half of exchange slice (loads flew under MFMA) ----
    if (tt != 0) {
      asm volatile("s_waitcnt vmcnt(0)" ::: "memory");
      __builtin_amdgcn_sched_barrier(0);
#pragma unroll
      for (int p = 0; p < 4; ++p) {
        int gcbl = 2 + (p >> 1), ch = (p & 1) * 64 + lane;
        int rowl = ch >> 3, c8 = ch & 7;
        int gcb  = wv * 4 + gcbl;
        int bo = (((rowl << 11) + gcb * 128 + c8 * 16) ^ ((rowl & 7) << 4));
        *reinterpret_cast<uint4v*>(reinterpret_cast<char*>(Ahi) + bo) = u1h[p];
        *reinterpret_cast<uint4v*>(reinterpret_cast<char*>(Alo) + bo) = u1l[p];
      }
      asm volatile("s_waitcnt lgkmcnt(0)" ::: "memory");
      __builtin_amdgcn_sched_barrier(0);
    }

    // ---- MFMA kkl 4..7 ----
    MFMA_Q(4, 8)
    asm volatile("s_nop 7\n\ts_nop 7");   // MFMA -> VALU acc-read hazard

    // ---- combine + partial write to LDS ----
#pragma unroll
    for (int c = 0; c < 4; ++c) {
      float4v pv;
#pragma unroll
      for (int j = 0; j < 4; ++j)
        pv[j] = ac1[c][j] + (ac2[c][j] + ac3[c][j]) * LOINV;
      *reinterpret_cast<float4v*>(&part[(wv * 64 + c * 16 + cn) * 20 + kg * 4]) = pv;
    }
    __syncthreads();

    // ---- reduce 4 waves' partials (owner role: col wcol, rows kg*4+j) ----
    float4v vs = {};
#pragma unroll
    for (int w = 0; w < 4; ++w) {
      float4v pw = *reinterpret_cast<const float4v*>(
          &part[(w * 64 + wv * 16 + cn) * 20 + kg * 4]);
#pragma unroll
      for (int j = 0; j < 4; ++j) vs[j] += pw[j];
    }
    asm volatile("s_waitcnt vmcnt(0)" ::: "memory");  // xi arrived (free in steady state)

    // ---- epilogue ----
    const int tglob = t0 + tt;
    const int par = (tt + 1) & 1;
    _Float16* WHi = par ? hexHiA : hexHiB;
    _Float16* WLo = par ? hexLoA : hexLoB;
#pragma unroll
    for (int j = 0; j < 4; ++j) {
      int rowl = kg * 4 + j;
      int row  = r0 + rowl;
      float v = vs[j] + bhv + (float)bits16((unsigned short)xr[j]);
      float ex = __expf(2.0f * v);
      float h  = 1.0f - 2.0f / (ex + 1.0f);
      if (tt < Tc - 1) {
        FU16 thi, tlo;
        thi.f = (_Float16)h;
        tlo.f = (_Float16)((h - (float)thi.f) * LOSCALE);
        size_t off = (((size_t)(gb * 16 + gc)) << 10) + rowl * 64 + wv * 16 + cn;
        asm volatile("global_store_short %0, %1, off sc0 sc1"
                     :: "v"((unsigned long long)(WHi + off)), "v"((unsigned int)thi.u) : "memory");
        asm volatile("global_store_short %0, %1, off sc0 sc1"
                     :: "v"((unsigned long long)(WLo + off)), "v"((unsigned int)tlo.u) : "memory");
      }
      if (tglob == SEQT - 1) out[(((size_t)row) << 10) + wcol] = h;
      else if (tt == Tc - 1) hstate[(((size_t)row) << 10) + wcol] = h;
    }
    if (tt == Tc - 1) break;  // no barrier/exchange after final step of chunk

    // ---- drain h stores, rendezvous, publish flag ----
    asm volatile("s_waitcnt vmcnt(0)" ::: "memory");
    __builtin_amdgcn_s_barrier();
    const int target = tt + 1;
    if (tid == 0)
      asm volatile("global_store_dword %0, %1, off sc0 sc1"
                   :: "v"((unsigned long long)(bar + (gb * 16 + gc) * 32)),
                      "v"(target) : "memory");

    // xi prefetch for step tt+1 (in flight through poll + exchange)
#pragma unroll
    for (int j = 0; j < 4; ++j) {
      unsigned long long ap = (unsigned long long)
          (xi + xibase + (((size_t)(tt + 1)) << 18) + (size_t)(kg * 4 + j) * 64);
      asm volatile("global_load_ushort %0, %1, off" : "=v"(xr[j]) : "v"(ap) : "memory");
    }

    // ---- poll all 16 producer flags (16 lanes in parallel), then gate ----
    if (tid < 16) {
      const int* fp = bar + (gb * 16 + tid) * 32;
      for (;;) {
        int v;
        asm volatile("global_load_dword %0, %1, off sc0 sc1\n\t"
                     "s_waitcnt vmcnt(0)"
                     : "=v"(v) : "v"((unsigned long long)fp) : "memory");
        if (v >= target) break;
        __builtin_amdgcn_s_sleep(1);
      }
    }
    __builtin_amdgcn_s_barrier();

    // ---- wave-private exchange: wave wv loads cols wv*256..+255 (gcb wv*4..wv*4+3) ----
    const _Float16* SHi = par ? hexHiA : hexHiB;
    const _Float16* SLo = par ? hexLoA : hexLoB;
    uint4v u0h[4], u0l[4];
#pragma unroll
    for (int p = 0; p < 4; ++p) {
      int gcbl = p >> 1, ch = (p & 1) * 64 + lane;
      int rowl = ch >> 3, c8 = ch & 7;
      int gcb  = wv * 4 + gcbl;
      size_t off = (((size_t)(gb * 16 + gcb)) << 10) + rowl * 64 + c8 * 8;
      asm volatile("global_load_dwordx4 %0, %1, off sc0 sc1"
                   : "=v"(u0h[p]) : "v"((unsigned long long)(SHi + off)) : "memory");
      asm volatile("global_load_dwordx4 %0, %1, off sc0 sc1"
                   : "=v"(u0l[p]) : "v"((unsigned long long)(SLo + off)) : "memory");
    }
#pragma unroll
    for (int p = 0; p < 4; ++p) {
      int gcbl = 2 + (p >> 1), ch = (p & 1) * 64 + lane;
      int rowl = ch >> 3, c8 = ch & 7;
      int gcb  = wv * 4 + gcbl;
      size_t off = (((size_t)(gb * 16 + gcb)) << 10) + rowl * 64 + c8 * 8;
      asm volatile("global_load_dwordx4 %0, %1, off sc0 sc1"
                   : "=v"(u1h[p]) : "v"((unsigned long long)(SHi + off)) : "memory");
      asm volatile("global_load_dwordx4 %0, %1, off sc0 sc1"
                   : "=v"(u1l[p]) : "v"((unsigned long long)(SLo + off)) : "memory");
    }
    // first 8 loads done; 8 stay in flight across loop top (land before kkl 4..7)
    asm volatile("s_waitcnt vmcnt(8)" ::: "memory");
    __builtin_amdgcn_sched_barrier(0);
#pragma unroll
    for (int p = 0; p < 4; ++p) {
      int gcbl = p >> 1, ch = (p & 1) * 64 + lane;
      int rowl = ch >> 3, c8 = ch & 7;
      int gcb  = wv * 4 + gcbl;
      int bo = (((rowl << 11) + gcb * 128 + c8 * 16) ^ ((rowl & 7) << 4));
      *reinterpret_cast<uint4v*>(reinterpret_cast<char*>(Ahi) + bo) = u0h[p];
      *reinterpret_cast<uint4v*>(reinterpret_cast<char*>(Alo) + bo) = u0l[p];
    }
    asm volatile("s_waitcnt lgkmcnt(0)" ::: "memory");
    __builtin_amdgcn_sched_barrier(0);
    // no barrier: LDS region is wave-private; loop to MFMA kkl 0..3
  }
#undef MFMA_Q
}

extern "C" void kernel_launch(void* const* d_in, const int* in_sizes, int n_in,
                              void* d_out, int out_size, void* d_ws, size_t ws_size,
                              hipStream_t stream) {
  const int*   x   = (const int*)  d_in[0];
  const float* emb = (const float*)d_in[1];
  const float* Wi  = (const float*)d_in[2];
  const float* bi  = (const float*)d_in[3];
  const float* Wh  = (const float*)d_in[4];
  const float* bh  = (const float*)d_in[5];
  float* out = (float*)d_out;

  char* ws = (char*)d_ws;
  size_t off = 0;
  auto alloc = [&](size_t bytes) -> void* {
    void* p = ws + off;
    off = (off + bytes + 255) & ~(size_t)255;
    return p;
  };

  _Float16* embh   = (_Float16*)alloc((size_t)VOCABN * EMBED * 2);
  _Float16* Wih    = (_Float16*)alloc((size_t)HID * EMBED * 2);
  _Float16* Whih   = (_Float16*)alloc((size_t)HID * HID * 2);
  _Float16* Wloh   = (_Float16*)alloc((size_t)HID * HID * 2);
  float*    hstate = (float*)   alloc((size_t)BATCHN * HID * 4);
  _Float16* hexHiA = (_Float16*)alloc((size_t)BATCHN * HID * 2);
  _Float16* hexLoA = (_Float16*)alloc((size_t)BATCHN * HID * 2);
  _Float16* hexHiB = (_Float16*)alloc((size_t)BATCHN * HID * 2);
  _Float16* hexLoB = (_Float16*)alloc((size_t)BATCHN * HID * 2);
  int* bar  = (int*)alloc(256 * 32 * 4);   // 128B flag line per WG
  size_t fixed = off;

  // largest power-of-two T-chunk whose xi buffer fits in remaining ws
  int Tc = 1024;
  while (Tc > 4 && fixed + (size_t)BATCHN * Tc * HID * 2 > ws_size) Tc >>= 1;
  _Float16* xih = (_Float16*)alloc((size_t)BATCHN * Tc * HID * 2);

  {
    int n = VOCABN * EMBED;
    convert_f32_f16<<<n / 1024, 256, 0, stream>>>(emb, embh, n);
    n = HID * EMBED;
    convert_f32_f16<<<n / 1024, 256, 0, stream>>>(Wi, Wih, n);
    n = HID * HID;
    split_f32_f16<<<n / 1024, 256, 0, stream>>>(Wh, Whih, Wloh, n);
  }

  for (int t0 = 0; t0 < SEQT; t0 += Tc) {
    int grid = (BATCHN * Tc / 128) * 8;  // 128x128 tiles over [256*Tc, 1024]
    gemm_xi<<<grid, 256, 0, stream>>>(embh, Wih, x, bi, xih, t0, Tc);
    hipMemsetAsync(bar, 0, 256 * 32 * 4, stream);
    rnn_scan<<<256, 256, 0, stream>>>(Whih, Wloh, bh, xih, hstate, out,
                                      hexHiA, hexLoA, hexHiB, hexLoB, bar, t0, Tc);
  }
}